// Round 13
// baseline (29.204 us; speedup 1.0000x reference)
//
#include <hip/hip_runtime.h>
#include <math.h>

#define NF 50
#define REC 52           // per-block record: 50 z + s + pad
#define NBLK 512         // 2 blocks/CU at (512,4) -> exactly co-resident
#define LOG2E 1.44269504f

// DPP ctrl codes
#define DPP_QXOR1 0xB1   // quad_perm [1,0,3,2]
#define DPP_QXOR2 0x4E   // quad_perm [2,3,0,1]
#define DPP_ROR4  0x124  // row_ror:4
#define DPP_ROR8  0x128  // row_ror:8

__device__ __forceinline__ float dpp_add(float v, int ctrl) {
    float t;
    switch (ctrl) {  // ctrl must be an ICE for the builtin
      case DPP_QXOR1: t = __int_as_float(__builtin_amdgcn_update_dpp(0, __float_as_int(v), DPP_QXOR1, 0xF, 0xF, true)); break;
      case DPP_QXOR2: t = __int_as_float(__builtin_amdgcn_update_dpp(0, __float_as_int(v), DPP_QXOR2, 0xF, 0xF, true)); break;
      case DPP_ROR4:  t = __int_as_float(__builtin_amdgcn_update_dpp(0, __float_as_int(v), DPP_ROR4,  0xF, 0xF, true)); break;
      default:        t = __int_as_float(__builtin_amdgcn_update_dpp(0, __float_as_int(v), DPP_ROR8,  0xF, 0xF, true)); break;
    }
    return v + t;
}

// t = 1/(e^{2qWx}+1) building block (tanh = 1-2t); exp2-based.
#define RCPE(v) __builtin_amdgcn_rcpf(__builtin_amdgcn_exp2f(c2 * (v)) + 1.f)

// Pass 1: R8 champion, verbatim. One hardware quad (4 lanes) per row;
// lane q owns float2 slots q+4t (t=0..5) plus a 7th slot (real slot 24
// for q==0; same-line dummy with zero weight otherwise).
// score = sumW - 2*sum_f w_f/(e^{2qWx}+1); e = exp2(K - 2log2e * p).
// 512 blocks x 512 thr = 2 blocks/CU all resident; (512,4) -> <=128 VGPR.
__global__ __launch_bounds__(512, 4) void attn_pass1(
    const float* __restrict__ query, const float* __restrict__ ql_w,
    const float* __restrict__ qWp, float* __restrict__ ws,
    int T, int totalGroups)
{
    const float qW = qWp[0];
    const int tid = threadIdx.x;
    const int q   = tid & 3;                       // lane within quad
    const int g   = blockIdx.x * 128 + (tid >> 2); // global group id (row stream)

    // per-lane weights for slots q+4t
    float2 w01[7];
    #pragma unroll
    for (int t = 0; t < 6; ++t) {
        const int s = q + 4 * t;
        w01[t] = *(const float2*)(ql_w + 2 * s);
    }
    w01[6] = (q == 0) ? *(const float2*)(ql_w + 48) : make_float2(0.f, 0.f);
    const int d6 = (q == 0) ? 192 : 160;           // 7th-slot byte offset from rp

    // sumW / sumAbsW: per-lane partial over its slots, then quad reduce.
    float sw = 0.f, saw = 0.f;
    #pragma unroll
    for (int t = 0; t < 7; ++t) {
        sw  += w01[t].x + w01[t].y;
        saw += fabsf(w01[t].x) + fabsf(w01[t].y);
    }
    sw  = dpp_add(dpp_add(sw,  DPP_QXOR1), DPP_QXOR2);
    saw = dpp_add(dpp_add(saw, DPP_QXOR1), DPP_QXOR2);
    const float M0  = (saw > 80.f) ? (saw - 80.f) : 0.f;   // overflow guard; 0 here
    const float c2  = 2.f * qW * LOG2E;
    const float K   = (sw - M0) * LOG2E;
    const float n2l = -2.f * LOG2E;

    float2 z[7];
    #pragma unroll
    for (int t = 0; t < 7; ++t) z[t] = make_float2(0.f, 0.f);
    float se = 0.f;

    const int G = totalGroups;                     // NBLK*128 = 65536
    const char* rp = (const char*)(query + (size_t)g * NF) + (q << 3);
    const size_t step = (size_t)G * NF * sizeof(float);

    for (int row = g; row < T; row += G, rp += step) {
        float2 x0 = *(const float2*)(rp);
        float2 x1 = *(const float2*)(rp + 32);
        float2 x2 = *(const float2*)(rp + 64);
        float2 x3 = *(const float2*)(rp + 96);
        float2 x4 = *(const float2*)(rp + 128);
        float2 x5 = *(const float2*)(rp + 160);
        float2 x6 = *(const float2*)(rp + d6);

        float p = 0.f, r;
        r = RCPE(x0.x); p = fmaf(w01[0].x, r, p);
        r = RCPE(x0.y); p = fmaf(w01[0].y, r, p);
        r = RCPE(x1.x); p = fmaf(w01[1].x, r, p);
        r = RCPE(x1.y); p = fmaf(w01[1].y, r, p);
        r = RCPE(x2.x); p = fmaf(w01[2].x, r, p);
        r = RCPE(x2.y); p = fmaf(w01[2].y, r, p);
        r = RCPE(x3.x); p = fmaf(w01[3].x, r, p);
        r = RCPE(x3.y); p = fmaf(w01[3].y, r, p);
        r = RCPE(x4.x); p = fmaf(w01[4].x, r, p);
        r = RCPE(x4.y); p = fmaf(w01[4].y, r, p);
        r = RCPE(x5.x); p = fmaf(w01[5].x, r, p);
        r = RCPE(x5.y); p = fmaf(w01[5].y, r, p);
        r = RCPE(x6.x); p = fmaf(w01[6].x, r, p);
        r = RCPE(x6.y); p = fmaf(w01[6].y, r, p);

        p = dpp_add(dpp_add(p, DPP_QXOR1), DPP_QXOR2);  // full 50-feature sum
        const float e = __builtin_amdgcn_exp2f(fmaf(p, n2l, K));

        se += e;
        z[0].x = fmaf(e, x0.x, z[0].x); z[0].y = fmaf(e, x0.y, z[0].y);
        z[1].x = fmaf(e, x1.x, z[1].x); z[1].y = fmaf(e, x1.y, z[1].y);
        z[2].x = fmaf(e, x2.x, z[2].x); z[2].y = fmaf(e, x2.y, z[2].y);
        z[3].x = fmaf(e, x3.x, z[3].x); z[3].y = fmaf(e, x3.y, z[3].y);
        z[4].x = fmaf(e, x4.x, z[4].x); z[4].y = fmaf(e, x4.y, z[4].y);
        z[5].x = fmaf(e, x5.x, z[5].x); z[5].y = fmaf(e, x5.y, z[5].y);
        z[6].x = fmaf(e, x6.x, z[6].x); z[6].y = fmaf(e, x6.y, z[6].y);
    }

    // Sum the 4 quads within each 16-lane row (lanes l, l+4, l+8, l+12
    // share q and hold disjoint rows' partials for the same slots).
    #pragma unroll
    for (int t = 0; t < 7; ++t) {
        z[t].x = dpp_add(dpp_add(z[t].x, DPP_ROR4), DPP_ROR8);
        z[t].y = dpp_add(dpp_add(z[t].y, DPP_ROR4), DPP_ROR8);
    }
    se = dpp_add(dpp_add(se, DPP_ROR4), DPP_ROR8);

    __shared__ float sz[32][REC];
    if ((tid & 15) < 4) {                  // one writer per q per 16-row
        const int eidx = tid >> 4;         // 0..31
        #pragma unroll
        for (int t = 0; t < 6; ++t) {
            const int s = q + 4 * t;
            *(float2*)&sz[eidx][2 * s] = z[t];
        }
        if (q == 0) {
            *(float2*)&sz[eidx][48] = z[6];
            sz[eidx][50] = se;
            sz[eidx][51] = 0.f;
        }
    }
    __syncthreads();

    if (tid < 51) {
        float acc = 0.f;
        #pragma unroll
        for (int h = 0; h < 32; ++h) acc += sz[h][tid];
        ws[(size_t)blockIdx.x * REC + tid] = acc;
    }
}

// Pass 2: sum of B records via float4 lanes. 512 threads = 8 waves;
// wave w, lane l<13 reads rec[b][4l..4l+3] for b = w, w+8, ... (records
// are 52 floats = 13 float4, 16B-aligned since REC=52 and ws is aligned).
// Element 51 (never written by pass1) only ever lands in an accumulator
// component that is never read (final readers use f<51 only).
__global__ __launch_bounds__(512) void attn_pass2(
    const float* __restrict__ ws, float* __restrict__ out, int B)
{
    __shared__ float4 zacc[8][13];
    const int tid = threadIdx.x;
    const int w = tid >> 6, lane = tid & 63;

    if (lane < 13) {
        float4 acc = make_float4(0.f, 0.f, 0.f, 0.f);
        int b = w;
        for (; b + 24 < B; b += 32) {
            float4 v0 = *(const float4*)(ws + (size_t)(b     ) * REC + 4 * lane);
            float4 v1 = *(const float4*)(ws + (size_t)(b +  8) * REC + 4 * lane);
            float4 v2 = *(const float4*)(ws + (size_t)(b + 16) * REC + 4 * lane);
            float4 v3 = *(const float4*)(ws + (size_t)(b + 24) * REC + 4 * lane);
            acc.x += (v0.x + v1.x) + (v2.x + v3.x);
            acc.y += (v0.y + v1.y) + (v2.y + v3.y);
            acc.z += (v0.z + v1.z) + (v2.z + v3.z);
            acc.w += (v0.w + v1.w) + (v2.w + v3.w);
        }
        for (; b < B; b += 8) {
            float4 v = *(const float4*)(ws + (size_t)b * REC + 4 * lane);
            acc.x += v.x; acc.y += v.y; acc.z += v.z; acc.w += v.w;
        }
        zacc[w][lane] = acc;
    }
    __syncthreads();

    if (tid < NF) {
        const int c = tid >> 2, e = tid & 3;
        float Z = 0.f, S = 0.f;
        #pragma unroll
        for (int h = 0; h < 8; ++h) {
            const float4 v = zacc[h][c];
            Z += (e == 0) ? v.x : (e == 1) ? v.y : (e == 2) ? v.z : v.w;
            S += zacc[h][12].z;               // element 50
        }
        out[tid] = Z / S;
    }
}

extern "C" void kernel_launch(void* const* d_in, const int* in_sizes, int n_in,
                              void* d_out, int out_size, void* d_ws, size_t ws_size,
                              hipStream_t stream) {
    const float* query = (const float*)d_in[0];
    const float* ql_w  = (const float*)d_in[1];
    const float* qW    = (const float*)d_in[2];
    float* out = (float*)d_out;
    float* ws  = (float*)d_ws;

    const int T = in_sizes[0] / NF;

    int B = NBLK;
    size_t need = (size_t)B * REC * sizeof(float);
    if (ws_size < need) {
        B = (int)(ws_size / (REC * sizeof(float)));
        if (B < 1) B = 1;
    }

    const int totalGroups = B * 128;
    hipLaunchKernelGGL(attn_pass1, dim3(B), dim3(512), 0, stream,
                       query, ql_w, qW, ws, T, totalGroups);
    hipLaunchKernelGGL(attn_pass2, dim3(1), dim3(512), 0, stream,
                       ws, out, B);
}

// Round 14
// 25.772 us; speedup vs baseline: 1.1332x; 1.1332x over previous
//
#include <hip/hip_runtime.h>
#include <math.h>

#define NF 50
#define REC 52           // per-block record: 50 z + s + pad
#define NBLK 512         // 2 blocks/CU at (512,4) -> exactly co-resident
#define LOG2E 1.44269504f

// DPP ctrl codes
#define DPP_QXOR1 0xB1   // quad_perm [1,0,3,2]
#define DPP_QXOR2 0x4E   // quad_perm [2,3,0,1]
#define DPP_ROR4  0x124  // row_ror:4
#define DPP_ROR8  0x128  // row_ror:8

__device__ __forceinline__ float dpp_add(float v, int ctrl) {
    float t;
    switch (ctrl) {  // ctrl must be an ICE for the builtin
      case DPP_QXOR1: t = __int_as_float(__builtin_amdgcn_update_dpp(0, __float_as_int(v), DPP_QXOR1, 0xF, 0xF, true)); break;
      case DPP_QXOR2: t = __int_as_float(__builtin_amdgcn_update_dpp(0, __float_as_int(v), DPP_QXOR2, 0xF, 0xF, true)); break;
      case DPP_ROR4:  t = __int_as_float(__builtin_amdgcn_update_dpp(0, __float_as_int(v), DPP_ROR4,  0xF, 0xF, true)); break;
      default:        t = __int_as_float(__builtin_amdgcn_update_dpp(0, __float_as_int(v), DPP_ROR8,  0xF, 0xF, true)); break;
    }
    return v + t;
}

// t = 1/(e^{2qWx}+1) building block (tanh = 1-2t); exp2-based.
#define RCPE(v) __builtin_amdgcn_rcpf(__builtin_amdgcn_exp2f(c2 * (v)) + 1.f)

// Pass 1: R8 champion, verbatim. One hardware quad (4 lanes) per row;
// lane q owns float2 slots q+4t (t=0..5) plus a 7th slot (real slot 24
// for q==0; same-line dummy with zero weight otherwise).
// score = sumW - 2*sum_f w_f/(e^{2qWx}+1); e = exp2(K - 2log2e * p).
// 512 blocks x 512 thr = 2 blocks/CU all resident; (512,4) -> <=128 VGPR.
__global__ __launch_bounds__(512, 4) void attn_pass1(
    const float* __restrict__ query, const float* __restrict__ ql_w,
    const float* __restrict__ qWp, float* __restrict__ ws,
    int T, int totalGroups)
{
    const float qW = qWp[0];
    const int tid = threadIdx.x;
    const int q   = tid & 3;                       // lane within quad
    const int g   = blockIdx.x * 128 + (tid >> 2); // global group id (row stream)

    // per-lane weights for slots q+4t
    float2 w01[7];
    #pragma unroll
    for (int t = 0; t < 6; ++t) {
        const int s = q + 4 * t;
        w01[t] = *(const float2*)(ql_w + 2 * s);
    }
    w01[6] = (q == 0) ? *(const float2*)(ql_w + 48) : make_float2(0.f, 0.f);
    const int d6 = (q == 0) ? 192 : 160;           // 7th-slot byte offset from rp

    // sumW / sumAbsW: per-lane partial over its slots, then quad reduce.
    float sw = 0.f, saw = 0.f;
    #pragma unroll
    for (int t = 0; t < 7; ++t) {
        sw  += w01[t].x + w01[t].y;
        saw += fabsf(w01[t].x) + fabsf(w01[t].y);
    }
    sw  = dpp_add(dpp_add(sw,  DPP_QXOR1), DPP_QXOR2);
    saw = dpp_add(dpp_add(saw, DPP_QXOR1), DPP_QXOR2);
    const float M0  = (saw > 80.f) ? (saw - 80.f) : 0.f;   // overflow guard; 0 here
    const float c2  = 2.f * qW * LOG2E;
    const float K   = (sw - M0) * LOG2E;
    const float n2l = -2.f * LOG2E;

    float2 z[7];
    #pragma unroll
    for (int t = 0; t < 7; ++t) z[t] = make_float2(0.f, 0.f);
    float se = 0.f;

    const int G = totalGroups;                     // NBLK*128 = 65536
    const char* rp = (const char*)(query + (size_t)g * NF) + (q << 3);
    const size_t step = (size_t)G * NF * sizeof(float);

    for (int row = g; row < T; row += G, rp += step) {
        float2 x0 = *(const float2*)(rp);
        float2 x1 = *(const float2*)(rp + 32);
        float2 x2 = *(const float2*)(rp + 64);
        float2 x3 = *(const float2*)(rp + 96);
        float2 x4 = *(const float2*)(rp + 128);
        float2 x5 = *(const float2*)(rp + 160);
        float2 x6 = *(const float2*)(rp + d6);

        float p = 0.f, r;
        r = RCPE(x0.x); p = fmaf(w01[0].x, r, p);
        r = RCPE(x0.y); p = fmaf(w01[0].y, r, p);
        r = RCPE(x1.x); p = fmaf(w01[1].x, r, p);
        r = RCPE(x1.y); p = fmaf(w01[1].y, r, p);
        r = RCPE(x2.x); p = fmaf(w01[2].x, r, p);
        r = RCPE(x2.y); p = fmaf(w01[2].y, r, p);
        r = RCPE(x3.x); p = fmaf(w01[3].x, r, p);
        r = RCPE(x3.y); p = fmaf(w01[3].y, r, p);
        r = RCPE(x4.x); p = fmaf(w01[4].x, r, p);
        r = RCPE(x4.y); p = fmaf(w01[4].y, r, p);
        r = RCPE(x5.x); p = fmaf(w01[5].x, r, p);
        r = RCPE(x5.y); p = fmaf(w01[5].y, r, p);
        r = RCPE(x6.x); p = fmaf(w01[6].x, r, p);
        r = RCPE(x6.y); p = fmaf(w01[6].y, r, p);

        p = dpp_add(dpp_add(p, DPP_QXOR1), DPP_QXOR2);  // full 50-feature sum
        const float e = __builtin_amdgcn_exp2f(fmaf(p, n2l, K));

        se += e;
        z[0].x = fmaf(e, x0.x, z[0].x); z[0].y = fmaf(e, x0.y, z[0].y);
        z[1].x = fmaf(e, x1.x, z[1].x); z[1].y = fmaf(e, x1.y, z[1].y);
        z[2].x = fmaf(e, x2.x, z[2].x); z[2].y = fmaf(e, x2.y, z[2].y);
        z[3].x = fmaf(e, x3.x, z[3].x); z[3].y = fmaf(e, x3.y, z[3].y);
        z[4].x = fmaf(e, x4.x, z[4].x); z[4].y = fmaf(e, x4.y, z[4].y);
        z[5].x = fmaf(e, x5.x, z[5].x); z[5].y = fmaf(e, x5.y, z[5].y);
        z[6].x = fmaf(e, x6.x, z[6].x); z[6].y = fmaf(e, x6.y, z[6].y);
    }

    // Sum the 4 quads within each 16-lane row (lanes l, l+4, l+8, l+12
    // share q and hold disjoint rows' partials for the same slots).
    #pragma unroll
    for (int t = 0; t < 7; ++t) {
        z[t].x = dpp_add(dpp_add(z[t].x, DPP_ROR4), DPP_ROR8);
        z[t].y = dpp_add(dpp_add(z[t].y, DPP_ROR4), DPP_ROR8);
    }
    se = dpp_add(dpp_add(se, DPP_ROR4), DPP_ROR8);

    __shared__ float sz[32][REC];
    if ((tid & 15) < 4) {                  // one writer per q per 16-row
        const int eidx = tid >> 4;         // 0..31
        #pragma unroll
        for (int t = 0; t < 6; ++t) {
            const int s = q + 4 * t;
            *(float2*)&sz[eidx][2 * s] = z[t];
        }
        if (q == 0) {
            *(float2*)&sz[eidx][48] = z[6];
            sz[eidx][50] = se;
            sz[eidx][51] = 0.f;
        }
    }
    __syncthreads();

    if (tid < 51) {
        float acc = 0.f;
        #pragma unroll
        for (int h = 0; h < 32; ++h) acc += sz[h][tid];
        ws[(size_t)blockIdx.x * REC + tid] = acc;
    }
}

// Pass 2 (R8 verbatim): plain sum of B records (50 z + s each).
// 1024 threads = 16 waves; wave w, lanes 0..50 read one contiguous record
// slice (coalesced), 8-way unrolled -> 816 concurrent load streams.
__global__ __launch_bounds__(1024) void attn_pass2(
    const float* __restrict__ ws, float* __restrict__ out, int B)
{
    __shared__ float zacc[16][REC];
    const int tid = threadIdx.x;
    const int w = tid >> 6, lane = tid & 63;

    if (lane < 51) {
        float acc = 0.f;
        int b = w;
        for (; b + 112 < B; b += 128) {
            acc += ws[(size_t)(b      ) * REC + lane]
                 + ws[(size_t)(b +  16) * REC + lane]
                 + ws[(size_t)(b +  32) * REC + lane]
                 + ws[(size_t)(b +  48) * REC + lane]
                 + ws[(size_t)(b +  64) * REC + lane]
                 + ws[(size_t)(b +  80) * REC + lane]
                 + ws[(size_t)(b +  96) * REC + lane]
                 + ws[(size_t)(b + 112) * REC + lane];
        }
        for (; b < B; b += 16)
            acc += ws[(size_t)b * REC + lane];
        zacc[w][lane] = acc;
    }
    __syncthreads();
    if (tid < NF) {
        float Z = 0.f, S = 0.f;
        #pragma unroll
        for (int h = 0; h < 16; ++h) { Z += zacc[h][tid]; S += zacc[h][50]; }
        out[tid] = Z / S;
    }
}

extern "C" void kernel_launch(void* const* d_in, const int* in_sizes, int n_in,
                              void* d_out, int out_size, void* d_ws, size_t ws_size,
                              hipStream_t stream) {
    const float* query = (const float*)d_in[0];
    const float* ql_w  = (const float*)d_in[1];
    const float* qW    = (const float*)d_in[2];
    float* out = (float*)d_out;
    float* ws  = (float*)d_ws;

    const int T = in_sizes[0] / NF;

    int B = NBLK;
    size_t need = (size_t)B * REC * sizeof(float);
    if (ws_size < need) {
        B = (int)(ws_size / (REC * sizeof(float)));
        if (B < 1) B = 1;
    }

    const int totalGroups = B * 128;
    hipLaunchKernelGGL(attn_pass1, dim3(B), dim3(512), 0, stream,
                       query, ql_w, qW, ws, T, totalGroups);
    hipLaunchKernelGGL(attn_pass2, dim3(1), dim3(1024), 0, stream,
                       ws, out, B);
}